// Round 8
// baseline (1303.959 us; speedup 1.0000x reference)
//
#include <hip/hip_runtime.h>
#include <hip/hip_bf16.h>
#include <math.h>

#define B_   512
#define H_   512
#define FIN_ 1024
#define TS_  128

typedef __attribute__((ext_vector_type(8))) short short8;
typedef __attribute__((ext_vector_type(4))) float f32x4;

static __device__ __forceinline__ short f2bf(float f) {
    __hip_bfloat16 b = __float2bfloat16(f);
    return __builtin_bit_cast(short, b);
}
static __device__ __forceinline__ float bf2f(short s) {
    unsigned int u = ((unsigned int)(unsigned short)s) << 16;
    return __builtin_bit_cast(float, u);
}

// ---------------- weight prepack (once per call) ----------------
// Wpk2 fragment-packed bf16 pairs:
//   [jt 0..31][kt 0..15][g 0..5][sel 0..1 (hi/lo)][lane 0..63][i 0..7]
// B-frag (16x16x32): lane holds B[k = kt*32 + (lane>>4)*8 + i][j = jt*16 + (lane&15)]
__global__ __launch_bounds__(384)
void pack_weights(const float* __restrict__ Wih, const float* __restrict__ Whh,
                  short* __restrict__ Wpk2) {
    int jt = blockIdx.x;              // 0..31
    int kt = blockIdx.y;              // 0..15
    int g    = threadIdx.x >> 6;      // 0..5
    int lane = threadIdx.x & 63;
    int j = jt * 16 + (lane & 15);
    int k = kt * 32 + (lane >> 4) * 8;
    const float* src = (g < 3) ? &Wih[(size_t)(g * H_ + j) * H_ + k]
                               : &Whh[(size_t)((g - 3) * H_ + j) * H_ + k];
    short8 vhi, vlo;
#pragma unroll
    for (int i = 0; i < 8; ++i) {
        float w  = src[i];
        short hi = f2bf(w);
        vhi[i] = hi;
        vlo[i] = f2bf(w - bf2f(hi));
    }
    size_t base = ((((size_t)(jt * 16 + kt) * 6 + g) * 2) * 64 + lane) * 8;
    *reinterpret_cast<short8*>(&Wpk2[base])       = vhi;
    *reinterpret_cast<short8*>(&Wpk2[base + 512]) = vlo;
}

// WlinT[k][j] = W_lin[j][k], [1024][512]
__global__ void transpose_lin(const float* __restrict__ Wlin,
                              float* __restrict__ Wt) {
    __shared__ float t[32][33];
    int j0 = blockIdx.x * 32, k0 = blockIdx.y * 32;
    int kk = threadIdx.x, jj = threadIdx.y;
#pragma unroll
    for (int r = 0; r < 32; r += 8)
        t[jj + r][kk] = Wlin[(size_t)(j0 + jj + r) * FIN_ + k0 + kk];
    __syncthreads();
#pragma unroll
    for (int r = 0; r < 32; r += 8)
        Wt[(size_t)(k0 + jj + r) * H_ + j0 + kk] = t[kk][jj + r];
}

// ---------------- h0 = x @ WlinT + b_lin  (fp32, writes hi/lo bf16 split) ----------------
__global__ __launch_bounds__(256)
void gemm_h0(const float* __restrict__ X, const float* __restrict__ Wt,
             const float* __restrict__ bias,
             short* __restrict__ Hhi, short* __restrict__ Hlo) {
    const int BM = 32, BN = 32, BK = 32;
    __shared__ float xs[BK][BM + 2];
    __shared__ float ws[BK][BN];
    int b0 = blockIdx.y * BM, j0 = blockIdx.x * BN;
    int tid = threadIdx.x;
    int tx = tid & 15, ty = tid >> 4;
    float acc[2][2] = {};
    for (int k0 = 0; k0 < FIN_; k0 += BK) {
#pragma unroll
        for (int l = 0; l < 2; ++l) {
            int e = tid + l * 256;
            int krel = (e & 15) * 2, brel = e >> 4;
            float2 v = *(const float2*)&X[(size_t)(b0 + brel) * FIN_ + k0 + krel];
            xs[krel][brel] = v.x; xs[krel + 1][brel] = v.y;
        }
        {
            int fe = tid;
            int j4 = fe & 7, krel = fe >> 3;
            *(float4*)&ws[krel][j4 * 4] =
                *(const float4*)&Wt[(size_t)(k0 + krel) * H_ + j0 + j4 * 4];
        }
        __syncthreads();
#pragma unroll
        for (int kk = 0; kk < BK; ++kk) {
            float2 a = *(const float2*)&xs[kk][ty * 2];
            float2 w = *(const float2*)&ws[kk][tx * 2];
            acc[0][0] += a.x * w.x; acc[0][1] += a.x * w.y;
            acc[1][0] += a.y * w.x; acc[1][1] += a.y * w.y;
        }
        __syncthreads();
    }
#pragma unroll
    for (int r = 0; r < 2; ++r)
#pragma unroll
        for (int c = 0; c < 2; ++c) {
            int b = b0 + ty * 2 + r, j = j0 + tx * 2 + c;
            float v = acc[r][c] + bias[j];
            short hi = f2bf(v);
            Hhi[(size_t)b * H_ + j] = hi;
            Hlo[(size_t)b * H_ + j] = f2bf(v - bf2f(hi));
        }
}

// ---------------- persistent GRU: all 128 steps in one kernel ----------------
// 256 blocks, 512 threads (8 waves). Block = (row-group m = bid&7 -> 64 rows,
// jt = bid>>3 -> 16 cols). h stores are NONTEMPORAL (land at L3, the shared
// coherence point). h A-loads are CACHED (L2 serves the 32-block broadcast
// within a row-group when co-XCD; perf-only assumption). Cross-step
// correctness regardless of placement: per-step acquire-fence (L1/L2 inv)
// after a flag-array barrier (no atomic RMW; 32 parallel flag polls).
__global__ __launch_bounds__(512, 2)
void gru_persist(const short* __restrict__ Wpk2,
                 const float* __restrict__ bp,
                 short* __restrict__ hHiA, short* __restrict__ hLoA,
                 short* __restrict__ hHiB, short* __restrict__ hLoB,
                 float* __restrict__ out,
                 unsigned int* __restrict__ flags) {
    int bid  = blockIdx.x;
    int m    = bid & 7;            // row group (8 groups x 64 rows)
    int jt   = bid >> 3;           // 0..31
    int m0   = m * 64;
    int tid  = threadIdx.x;
    int w    = tid >> 6;           // wave 0..7
    int lane = tid & 63;

    unsigned int* gflags = flags + m * 128;   // 32 flags in one 128B line; groups 512B apart

    __shared__ float red[4][4][6][64][4];   // 4 bufs x 24 KB = 96 KB

    // ---- prologue: persistent W fragments ----
    short8 Wf[2][6][2];
#pragma unroll
    for (int kk = 0; kk < 2; ++kk) {
        int kt = 2 * w + kk;
        const short* wb = &Wpk2[((size_t)(jt * 16 + kt) * 6) * 1024 + lane * 8];
#pragma unroll
        for (int g = 0; g < 6; ++g) {
            Wf[kk][g][0] = *(const short8*)&wb[(size_t)g * 1024];
            Wf[kk][g][1] = *(const short8*)&wb[(size_t)g * 1024 + 512];
        }
    }

    // ---- epilogue mapping: thread owns 2 outputs (same row, adjacent cols) ----
    int o0   = tid * 2;
    int erow = o0 >> 4;            // 0..63 block-local row
    int ecol = o0 & 15;            // even col 0..14
    int gr   = m0 + erow;          // global row
    int gc0  = jt * 16 + ecol, gc1 = gc0 + 1;
    float eb0[6], eb1[6];
#pragma unroll
    for (int g = 0; g < 6; ++g) { eb0[g] = bp[g * H_ + gc0]; eb1[g] = bp[g * H_ + gc1]; }
    int emf   = erow >> 4;
    int elane = ((erow & 15) >> 2) << 4;
    int ev    = erow & 3;

    size_t i0 = (size_t)gr * H_ + gc0;
    size_t i1 = (size_t)gr * H_ + gc1;
    // h_prev carried in registers (initial h0 from gemm_h0 output)
    float hp0 = bf2f(hHiA[i0]) + bf2f(hLoA[i0]);
    float hp1 = bf2f(hHiA[i1]) + bf2f(hLoA[i1]);

    const short* curHi = hHiA; const short* curLo = hLoA;
    short* nxtHi = hHiB; short* nxtLo = hLoB;

    int arow  = m0 + (lane & 15);
    int akoff = (lane >> 4) * 8;

    for (int t = 0; t < TS_; ++t) {
        f32x4 acc[4][6] = {};
#pragma unroll
        for (int kk = 0; kk < 2; ++kk) {
            int kbase = (2 * w + kk) * 32 + akoff;
#pragma unroll
            for (int mf = 0; mf < 4; ++mf) {
                size_t aoff = (size_t)(arow + 16 * mf) * H_ + kbase;
                short8 ahi = *(const short8*)&curHi[aoff];   // cached: L2 broadcast
                short8 alo = *(const short8*)&curLo[aoff];
                if (t > 0) {
#pragma unroll
                    for (int g = 0; g < 3; ++g) {
                        acc[mf][g] = __builtin_amdgcn_mfma_f32_16x16x32_bf16(ahi, Wf[kk][g][0], acc[mf][g], 0, 0, 0);
                        acc[mf][g] = __builtin_amdgcn_mfma_f32_16x16x32_bf16(ahi, Wf[kk][g][1], acc[mf][g], 0, 0, 0);
                        acc[mf][g] = __builtin_amdgcn_mfma_f32_16x16x32_bf16(alo, Wf[kk][g][0], acc[mf][g], 0, 0, 0);
                    }
                }
#pragma unroll
                for (int g = 3; g < 6; ++g) {
                    acc[mf][g] = __builtin_amdgcn_mfma_f32_16x16x32_bf16(ahi, Wf[kk][g][0], acc[mf][g], 0, 0, 0);
                    acc[mf][g] = __builtin_amdgcn_mfma_f32_16x16x32_bf16(ahi, Wf[kk][g][1], acc[mf][g], 0, 0, 0);
                    acc[mf][g] = __builtin_amdgcn_mfma_f32_16x16x32_bf16(alo, Wf[kk][g][0], acc[mf][g], 0, 0, 0);
                }
            }
        }

        // ---- split-K tree reduction in LDS ----
        if (w >= 4) {
#pragma unroll
            for (int mf = 0; mf < 4; ++mf)
#pragma unroll
                for (int g = 0; g < 6; ++g)
                    *(f32x4*)&red[w - 4][mf][g][lane][0] = acc[mf][g];
        }
        __syncthreads();
        if (w < 4) {
#pragma unroll
            for (int mf = 0; mf < 4; ++mf)
#pragma unroll
                for (int g = 0; g < 6; ++g)
                    acc[mf][g] += *(const f32x4*)&red[w][mf][g][lane][0];
        }
        __syncthreads();
        if (w == 2 || w == 3) {
#pragma unroll
            for (int mf = 0; mf < 4; ++mf)
#pragma unroll
                for (int g = 0; g < 6; ++g)
                    *(f32x4*)&red[w - 2][mf][g][lane][0] = acc[mf][g];
        }
        __syncthreads();
        if (w < 2) {
#pragma unroll
            for (int mf = 0; mf < 4; ++mf)
#pragma unroll
                for (int g = 0; g < 6; ++g)
                    acc[mf][g] += *(const f32x4*)&red[w][mf][g][lane][0];
        }
        __syncthreads();
        if (w == 1) {
#pragma unroll
            for (int mf = 0; mf < 4; ++mf)
#pragma unroll
                for (int g = 0; g < 6; ++g)
                    *(f32x4*)&red[0][mf][g][lane][0] = acc[mf][g];
        }
        __syncthreads();
        if (w == 0) {
#pragma unroll
            for (int mf = 0; mf < 4; ++mf)
#pragma unroll
                for (int g = 0; g < 6; ++g) {
                    acc[mf][g] += *(const f32x4*)&red[0][mf][g][lane][0];
                    *(f32x4*)&red[1][mf][g][lane][0] = acc[mf][g];
                }
        }
        __syncthreads();

        // ---- epilogue: gate math, 2 outputs per thread, hp in registers ----
        {
            float v0[6], v1[6];
#pragma unroll
            for (int g = 0; g < 6; ++g) {
                v0[g] = red[1][emf][g][elane + ecol][ev];
                v1[g] = red[1][emf][g][elane + ecol + 1][ev];
            }
            float rg0 = 1.f / (1.f + expf(-((v0[0] + eb0[0]) + (v0[3] + eb0[3]))));
            float zg0 = 1.f / (1.f + expf(-((v0[1] + eb0[1]) + (v0[4] + eb0[4]))));
            float ng0 = tanhf((v0[2] + eb0[2]) + rg0 * (v0[5] + eb0[5]));
            float hn0 = (1.f - zg0) * ng0 + zg0 * hp0;

            float rg1 = 1.f / (1.f + expf(-((v1[0] + eb1[0]) + (v1[3] + eb1[3]))));
            float zg1 = 1.f / (1.f + expf(-((v1[1] + eb1[1]) + (v1[4] + eb1[4]))));
            float ng1 = tanhf((v1[2] + eb1[2]) + rg1 * (v1[5] + eb1[5]));
            float hn1 = (1.f - zg1) * ng1 + zg1 * hp1;

            short h0i = f2bf(hn0), h1i = f2bf(hn1);
            __builtin_nontemporal_store(h0i, &nxtHi[i0]);
            __builtin_nontemporal_store(f2bf(hn0 - bf2f(h0i)), &nxtLo[i0]);
            __builtin_nontemporal_store(h1i, &nxtHi[i1]);
            __builtin_nontemporal_store(f2bf(hn1 - bf2f(h1i)), &nxtLo[i1]);
            size_t oo = (size_t)gr * (TS_ * H_) + (size_t)t * H_;
            __builtin_nontemporal_store(hn0, &out[oo + gc0]);
            __builtin_nontemporal_store(hn1, &out[oo + gc1]);
            hp0 = hn0; hp1 = hn1;
        }

        if (t < TS_ - 1) {
            // each wave drains its own nt stores, then block-wide barrier
            asm volatile("s_waitcnt vmcnt(0)" ::: "memory");
            __syncthreads();
            // release: all h of this block is at L3 -> publish flag (no RMW)
            if (tid == 0)
                __hip_atomic_store(&gflags[jt], (unsigned)(t + 1),
                                   __ATOMIC_RELAXED, __HIP_MEMORY_SCOPE_AGENT);
            // wave 0 polls all 32 flags of the group in parallel
            if (w == 0) {
                unsigned target = (unsigned)(t + 1);
                if (lane < 32) {
                    while (__hip_atomic_load(&gflags[lane], __ATOMIC_RELAXED,
                                             __HIP_MEMORY_SCOPE_AGENT) < target)
                        __builtin_amdgcn_s_sleep(1);
                }
                // acquire: invalidate L1 + this XCD's L2 so cached h reads refetch
                __builtin_amdgcn_fence(__ATOMIC_ACQUIRE, "agent");
            }
            __syncthreads();
            const short* th = curHi; const short* tl = curLo;
            curHi = nxtHi; curLo = nxtLo;
            nxtHi = (short*)th; nxtLo = (short*)tl;
        }
    }
}

extern "C" void kernel_launch(void* const* d_in, const int* in_sizes, int n_in,
                              void* d_out, int out_size, void* d_ws, size_t ws_size,
                              hipStream_t stream) {
    const float* x     = (const float*)d_in[0];
    const float* W_lin = (const float*)d_in[1];
    const float* b_lin = (const float*)d_in[2];
    const float* W_ih  = (const float*)d_in[3];
    const float* W_hh  = (const float*)d_in[4];
    const float* b_ih  = (const float*)d_in[5];
    const float* b_hh  = (const float*)d_in[6];
    float* out = (float*)d_out;

    char* wsb = (char*)d_ws;
    short* Wpk2  = (short*)(wsb);                    // 6291456 B
    float* WlinT = (float*)(wsb + 6291456);          // 2097152 B
    float* bp    = (float*)(wsb + 8388608);          // 12288 B
    short* hHiA  = (short*)(wsb + 8400896);          // 524288 B
    short* hLoA  = (short*)(wsb + 8925184);
    short* hHiB  = (short*)(wsb + 9449472);
    short* hLoB  = (short*)(wsb + 9973760);
    unsigned int* flags = (unsigned int*)(wsb + 10498048);  // 8 groups x 128 uints

    hipMemcpyAsync(bp,        b_ih, 1536 * sizeof(float), hipMemcpyDeviceToDevice, stream);
    hipMemcpyAsync(bp + 1536, b_hh, 1536 * sizeof(float), hipMemcpyDeviceToDevice, stream);
    hipMemsetAsync(flags, 0, 8 * 128 * sizeof(unsigned int), stream);

    pack_weights <<<dim3(32, 16), 384, 0, stream>>>(W_ih, W_hh, Wpk2);
    transpose_lin<<<dim3(16, 32), dim3(32, 8), 0, stream>>>(W_lin, WlinT);

    gemm_h0<<<dim3(16, 16), 256, 0, stream>>>(x, WlinT, b_lin, hHiA, hLoA);

    gru_persist<<<256, 512, 0, stream>>>(Wpk2, bp, hHiA, hLoA, hHiB, hLoB, out, flags);
}

// Round 9
// 1005.343 us; speedup vs baseline: 1.2970x; 1.2970x over previous
//
#include <hip/hip_runtime.h>
#include <hip/hip_bf16.h>
#include <math.h>

#define B_   512
#define H_   512
#define FIN_ 1024
#define TS_  128

typedef __attribute__((ext_vector_type(8))) _Float16 half8;
typedef __attribute__((ext_vector_type(4))) float f32x4;

// ---------------- weight prepack (once per call), fp16 single plane ----------
// Wpkh [jt 0..31][kt 0..15][g 0..5][lane 0..63][i 0..7] fp16
// B-frag (16x16x32): lane holds B[k = kt*32 + (lane>>4)*8 + i][j = jt*16 + (lane&15)]
__global__ __launch_bounds__(384)
void pack_weights(const float* __restrict__ Wih, const float* __restrict__ Whh,
                  _Float16* __restrict__ Wpkh) {
    int jt = blockIdx.x;              // 0..31
    int kt = blockIdx.y;              // 0..15
    int g    = threadIdx.x >> 6;      // 0..5
    int lane = threadIdx.x & 63;
    int j = jt * 16 + (lane & 15);
    int k = kt * 32 + (lane >> 4) * 8;
    const float* src = (g < 3) ? &Wih[(size_t)(g * H_ + j) * H_ + k]
                               : &Whh[(size_t)((g - 3) * H_ + j) * H_ + k];
    half8 v;
#pragma unroll
    for (int i = 0; i < 8; ++i) v[i] = (_Float16)src[i];
    size_t off = ((((size_t)(jt * 16 + kt) * 6 + g)) * 64 + lane) * 8;
    *reinterpret_cast<half8*>(&Wpkh[off]) = v;
}

// WlinT[k][j] = W_lin[j][k], [1024][512]
__global__ void transpose_lin(const float* __restrict__ Wlin,
                              float* __restrict__ Wt) {
    __shared__ float t[32][33];
    int j0 = blockIdx.x * 32, k0 = blockIdx.y * 32;
    int kk = threadIdx.x, jj = threadIdx.y;
#pragma unroll
    for (int r = 0; r < 32; r += 8)
        t[jj + r][kk] = Wlin[(size_t)(j0 + jj + r) * FIN_ + k0 + kk];
    __syncthreads();
#pragma unroll
    for (int r = 0; r < 32; r += 8)
        Wt[(size_t)(k0 + jj + r) * H_ + j0 + kk] = t[kk][jj + r];
}

// ------------- h0 = x @ WlinT + b_lin (fp32; writes fp16 plane + f32 plane) --
__global__ __launch_bounds__(256)
void gemm_h0(const float* __restrict__ X, const float* __restrict__ Wt,
             const float* __restrict__ bias,
             _Float16* __restrict__ H16, float* __restrict__ H32) {
    const int BM = 32, BN = 32, BK = 32;
    __shared__ float xs[BK][BM + 2];
    __shared__ float ws[BK][BN];
    int b0 = blockIdx.y * BM, j0 = blockIdx.x * BN;
    int tid = threadIdx.x;
    int tx = tid & 15, ty = tid >> 4;
    float acc[2][2] = {};
    for (int k0 = 0; k0 < FIN_; k0 += BK) {
#pragma unroll
        for (int l = 0; l < 2; ++l) {
            int e = tid + l * 256;
            int krel = (e & 15) * 2, brel = e >> 4;
            float2 v = *(const float2*)&X[(size_t)(b0 + brel) * FIN_ + k0 + krel];
            xs[krel][brel] = v.x; xs[krel + 1][brel] = v.y;
        }
        {
            int fe = tid;
            int j4 = fe & 7, krel = fe >> 3;
            *(float4*)&ws[krel][j4 * 4] =
                *(const float4*)&Wt[(size_t)(k0 + krel) * H_ + j0 + j4 * 4];
        }
        __syncthreads();
#pragma unroll
        for (int kk = 0; kk < BK; ++kk) {
            float2 a = *(const float2*)&xs[kk][ty * 2];
            float2 w = *(const float2*)&ws[kk][tx * 2];
            acc[0][0] += a.x * w.x; acc[0][1] += a.x * w.y;
            acc[1][0] += a.y * w.x; acc[1][1] += a.y * w.y;
        }
        __syncthreads();
    }
#pragma unroll
    for (int r = 0; r < 2; ++r)
#pragma unroll
        for (int c = 0; c < 2; ++c) {
            int b = b0 + ty * 2 + r, j = j0 + tx * 2 + c;
            float v = acc[r][c] + bias[j];
            H32[(size_t)b * H_ + j] = v;
            H16[(size_t)b * H_ + j] = (_Float16)v;
        }
}

// ---------------- persistent GRU: all 128 steps in one kernel ----------------
// 512 blocks x 256 thr (4 waves), 2 blocks/CU (LDS 48KB, VGPR capped by
// __launch_bounds__(256,2) -> co-residency guaranteed; >256 VGPR would
// deadlock the flag barrier). Block = (row-group m = bid&15 -> 32 rows,
// jt = bid>>4 -> 16 cols). Wave w owns kt = 4w..4w+3; fp16 W frags persist
// in VGPRs. h exchange: fp16 single plane, nontemporal stores+loads (L3 is
// the shared coherence point -> no cache maintenance). Barrier: per-group
// 32-flag line, RELAXED publish/poll, no fence. Two independent barrier
// groups per CU let sync wait overlap the co-resident block's compute.
__global__ __launch_bounds__(256, 2)
void gru_persist(const _Float16* __restrict__ Wpkh,
                 const float* __restrict__ bp,
                 const _Float16* __restrict__ h16A, _Float16* __restrict__ h16B,
                 const float* __restrict__ h0f32,
                 float* __restrict__ out,
                 unsigned int* __restrict__ flags) {
    int bid  = blockIdx.x;
    int m    = bid & 15;           // row group (16 groups x 32 rows)
    int jt   = bid >> 4;           // 0..31
    int m0   = m * 32;
    int tid  = threadIdx.x;
    int w    = tid >> 6;           // wave 0..3
    int lane = tid & 63;

    unsigned int* gflags = flags + m * 128;   // 32 flags in one 128B line

    __shared__ float red[2][2][6][64][4];     // 2 bufs x 24 KB = 48 KB

    // ---- prologue: persistent W fragments (4 kt x 6 gates, fp16) ----
    half8 Wf[4][6];
#pragma unroll
    for (int kk = 0; kk < 4; ++kk) {
        int kt = 4 * w + kk;
        const _Float16* wb = &Wpkh[((size_t)(jt * 16 + kt) * 6) * 512 + lane * 8];
#pragma unroll
        for (int g = 0; g < 6; ++g)
            Wf[kk][g] = *(const half8*)&wb[(size_t)g * 512];
    }

    // ---- epilogue mapping: thread owns 2 outputs (same row, adjacent cols) --
    int o0   = tid * 2;
    int erow = o0 >> 4;            // 0..31 block-local row
    int ecol = o0 & 15;            // even col
    int gr   = m0 + erow;          // global row
    int gc0  = jt * 16 + ecol, gc1 = gc0 + 1;
    float eb0[6], eb1[6];
#pragma unroll
    for (int g = 0; g < 6; ++g) { eb0[g] = bp[g * H_ + gc0]; eb1[g] = bp[g * H_ + gc1]; }
    int emf   = erow >> 4;
    int elane = ((erow & 15) >> 2) << 4;
    int ev    = erow & 3;

    size_t i0 = (size_t)gr * H_ + gc0;
    size_t i1 = (size_t)gr * H_ + gc1;
    float hp0 = h0f32[i0];
    float hp1 = h0f32[i1];

    const _Float16* cur = h16A;
    _Float16*       nxt = h16B;

    int arow  = m0 + (lane & 15);
    int akoff = (lane >> 4) * 8;

    for (int t = 0; t < TS_; ++t) {
        f32x4 acc[2][6] = {};
#pragma unroll
        for (int kk = 0; kk < 4; ++kk) {
            int kbase = (4 * w + kk) * 32 + akoff;
#pragma unroll
            for (int mf = 0; mf < 2; ++mf) {
                size_t aoff = (size_t)(arow + 16 * mf) * H_ + kbase;
                half8 a = __builtin_nontemporal_load((const half8*)&cur[aoff]);
                if (t > 0) {
#pragma unroll
                    for (int g = 0; g < 3; ++g)
                        acc[mf][g] = __builtin_amdgcn_mfma_f32_16x16x32_f16(a, Wf[kk][g], acc[mf][g], 0, 0, 0);
                }
#pragma unroll
                for (int g = 3; g < 6; ++g)
                    acc[mf][g] = __builtin_amdgcn_mfma_f32_16x16x32_f16(a, Wf[kk][g], acc[mf][g], 0, 0, 0);
            }
        }

        // ---- split-K reduction: 4 waves -> 2 rounds ----
        if (w >= 2) {
#pragma unroll
            for (int mf = 0; mf < 2; ++mf)
#pragma unroll
                for (int g = 0; g < 6; ++g)
                    *(f32x4*)&red[w - 2][mf][g][lane][0] = acc[mf][g];
        }
        __syncthreads();
        if (w < 2) {
#pragma unroll
            for (int mf = 0; mf < 2; ++mf)
#pragma unroll
                for (int g = 0; g < 6; ++g)
                    acc[mf][g] += *(const f32x4*)&red[w][mf][g][lane][0];
        }
        __syncthreads();
        if (w == 1) {
#pragma unroll
            for (int mf = 0; mf < 2; ++mf)
#pragma unroll
                for (int g = 0; g < 6; ++g)
                    *(f32x4*)&red[0][mf][g][lane][0] = acc[mf][g];
        }
        __syncthreads();
        if (w == 0) {
#pragma unroll
            for (int mf = 0; mf < 2; ++mf)
#pragma unroll
                for (int g = 0; g < 6; ++g) {
                    acc[mf][g] += *(const f32x4*)&red[0][mf][g][lane][0];
                    *(f32x4*)&red[1][mf][g][lane][0] = acc[mf][g];
                }
        }
        __syncthreads();

        // ---- epilogue: gate math, 2 outputs/thread, hp carried in registers --
        {
            float v0[6], v1[6];
#pragma unroll
            for (int g = 0; g < 6; ++g) {
                v0[g] = red[1][emf][g][elane + ecol][ev];
                v1[g] = red[1][emf][g][elane + ecol + 1][ev];
            }
            float rg0 = 1.f / (1.f + expf(-((v0[0] + eb0[0]) + (v0[3] + eb0[3]))));
            float zg0 = 1.f / (1.f + expf(-((v0[1] + eb0[1]) + (v0[4] + eb0[4]))));
            float ng0 = tanhf((v0[2] + eb0[2]) + rg0 * (v0[5] + eb0[5]));
            float hn0 = (1.f - zg0) * ng0 + zg0 * hp0;

            float rg1 = 1.f / (1.f + expf(-((v1[0] + eb1[0]) + (v1[3] + eb1[3]))));
            float zg1 = 1.f / (1.f + expf(-((v1[1] + eb1[1]) + (v1[4] + eb1[4]))));
            float ng1 = tanhf((v1[2] + eb1[2]) + rg1 * (v1[5] + eb1[5]));
            float hn1 = (1.f - zg1) * ng1 + zg1 * hp1;

            __builtin_nontemporal_store((_Float16)hn0, &nxt[i0]);
            __builtin_nontemporal_store((_Float16)hn1, &nxt[i1]);
            size_t oo = (size_t)gr * (TS_ * H_) + (size_t)t * H_;
            __builtin_nontemporal_store(hn0, &out[oo + gc0]);
            __builtin_nontemporal_store(hn1, &out[oo + gc1]);
            hp0 = hn0; hp1 = hn1;
        }

        if (t < TS_ - 1) {
            asm volatile("s_waitcnt vmcnt(0)" ::: "memory");   // nt stores at L3
            __syncthreads();                                   // also guards red[] reuse
            if (tid == 0)
                __hip_atomic_store(&gflags[jt], (unsigned)(t + 1),
                                   __ATOMIC_RELAXED, __HIP_MEMORY_SCOPE_AGENT);
            if (w == 0 && lane < 32) {
                unsigned target = (unsigned)(t + 1);
                while (__hip_atomic_load(&gflags[lane], __ATOMIC_RELAXED,
                                         __HIP_MEMORY_SCOPE_AGENT) < target)
                    __builtin_amdgcn_s_sleep(1);
            }
            __syncthreads();
            const _Float16* tc = cur;
            cur = nxt; nxt = (_Float16*)tc;
        }
    }
}

extern "C" void kernel_launch(void* const* d_in, const int* in_sizes, int n_in,
                              void* d_out, int out_size, void* d_ws, size_t ws_size,
                              hipStream_t stream) {
    const float* x     = (const float*)d_in[0];
    const float* W_lin = (const float*)d_in[1];
    const float* b_lin = (const float*)d_in[2];
    const float* W_ih  = (const float*)d_in[3];
    const float* W_hh  = (const float*)d_in[4];
    const float* b_ih  = (const float*)d_in[5];
    const float* b_hh  = (const float*)d_in[6];
    float* out = (float*)d_out;

    char* wsb = (char*)d_ws;
    _Float16* Wpkh  = (_Float16*)(wsb);              // 3145728 B
    float*    WlinT = (float*)(wsb + 3145728);       // 2097152 B
    float*    bp    = (float*)(wsb + 5242880);       // 12288 B
    _Float16* h16A  = (_Float16*)(wsb + 5255168);    // 524288 B
    _Float16* h16B  = (_Float16*)(wsb + 5779456);    // 524288 B
    float*    h0f32 = (float*)(wsb + 6303744);       // 1048576 B
    unsigned int* flags = (unsigned int*)(wsb + 7352320);  // 16 x 128 uints

    hipMemcpyAsync(bp,        b_ih, 1536 * sizeof(float), hipMemcpyDeviceToDevice, stream);
    hipMemcpyAsync(bp + 1536, b_hh, 1536 * sizeof(float), hipMemcpyDeviceToDevice, stream);
    hipMemsetAsync(flags, 0, 16 * 128 * sizeof(unsigned int), stream);

    pack_weights <<<dim3(32, 16), 384, 0, stream>>>(W_ih, W_hh, Wpkh);
    transpose_lin<<<dim3(16, 32), dim3(32, 8), 0, stream>>>(W_lin, WlinT);

    gemm_h0<<<dim3(16, 16), 256, 0, stream>>>(x, WlinT, b_lin, h16A, h0f32);

    gru_persist<<<512, 256, 0, stream>>>(Wpkh, bp, h16A, h16B, h0f32, out, flags);
}

// Round 11
// 847.021 us; speedup vs baseline: 1.5395x; 1.1869x over previous
//
#include <hip/hip_runtime.h>
#include <hip/hip_bf16.h>
#include <math.h>

#define B_   512
#define H_   512
#define FIN_ 1024
#define TS_  128

typedef __attribute__((ext_vector_type(8))) _Float16 half8;
typedef __attribute__((ext_vector_type(4))) float f32x4;
typedef __attribute__((ext_vector_type(2))) unsigned long long u64x2;

// ---------------- weight prepack (once per call), fp16 single plane ----------
// Wpkh [jt 0..31][kt 0..15][g 0..5][lane 0..63][i 0..7] fp16
// B-frag (16x16x32): lane holds B[k = kt*32 + (lane>>4)*8 + i][j = jt*16 + (lane&15)]
__global__ __launch_bounds__(384)
void pack_weights(const float* __restrict__ Wih, const float* __restrict__ Whh,
                  _Float16* __restrict__ Wpkh) {
    int jt = blockIdx.x;              // 0..31
    int kt = blockIdx.y;              // 0..15
    int g    = threadIdx.x >> 6;      // 0..5
    int lane = threadIdx.x & 63;
    int j = jt * 16 + (lane & 15);
    int k = kt * 32 + (lane >> 4) * 8;
    const float* src = (g < 3) ? &Wih[(size_t)(g * H_ + j) * H_ + k]
                               : &Whh[(size_t)((g - 3) * H_ + j) * H_ + k];
    half8 v;
#pragma unroll
    for (int i = 0; i < 8; ++i) v[i] = (_Float16)src[i];
    size_t off = ((((size_t)(jt * 16 + kt) * 6 + g)) * 64 + lane) * 8;
    *reinterpret_cast<half8*>(&Wpkh[off]) = v;
}

// WlinT[k][j] = W_lin[j][k], [1024][512]
__global__ void transpose_lin(const float* __restrict__ Wlin,
                              float* __restrict__ Wt) {
    __shared__ float t[32][33];
    int j0 = blockIdx.x * 32, k0 = blockIdx.y * 32;
    int kk = threadIdx.x, jj = threadIdx.y;
#pragma unroll
    for (int r = 0; r < 32; r += 8)
        t[jj + r][kk] = Wlin[(size_t)(j0 + jj + r) * FIN_ + k0 + kk];
    __syncthreads();
#pragma unroll
    for (int r = 0; r < 32; r += 8)
        Wt[(size_t)(k0 + jj + r) * H_ + j0 + kk] = t[kk][jj + r];
}

// ------------- h0 = x @ WlinT + b_lin (fp32; writes fp16 plane + f32 plane) --
__global__ __launch_bounds__(256)
void gemm_h0(const float* __restrict__ X, const float* __restrict__ Wt,
             const float* __restrict__ bias,
             _Float16* __restrict__ H16, float* __restrict__ H32) {
    const int BM = 32, BN = 32, BK = 32;
    __shared__ float xs[BK][BM + 2];
    __shared__ float ws[BK][BN];
    int b0 = blockIdx.y * BM, j0 = blockIdx.x * BN;
    int tid = threadIdx.x;
    int tx = tid & 15, ty = tid >> 4;
    float acc[2][2] = {};
    for (int k0 = 0; k0 < FIN_; k0 += BK) {
#pragma unroll
        for (int l = 0; l < 2; ++l) {
            int e = tid + l * 256;
            int krel = (e & 15) * 2, brel = e >> 4;
            float2 v = *(const float2*)&X[(size_t)(b0 + brel) * FIN_ + k0 + krel];
            xs[krel][brel] = v.x; xs[krel + 1][brel] = v.y;
        }
        {
            int fe = tid;
            int j4 = fe & 7, krel = fe >> 3;
            *(float4*)&ws[krel][j4 * 4] =
                *(const float4*)&Wt[(size_t)(k0 + krel) * H_ + j0 + j4 * 4];
        }
        __syncthreads();
#pragma unroll
        for (int kk = 0; kk < BK; ++kk) {
            float2 a = *(const float2*)&xs[kk][ty * 2];
            float2 w = *(const float2*)&ws[kk][tx * 2];
            acc[0][0] += a.x * w.x; acc[0][1] += a.x * w.y;
            acc[1][0] += a.y * w.x; acc[1][1] += a.y * w.y;
        }
        __syncthreads();
    }
#pragma unroll
    for (int r = 0; r < 2; ++r)
#pragma unroll
        for (int c = 0; c < 2; ++c) {
            int b = b0 + ty * 2 + r, j = j0 + tx * 2 + c;
            float v = acc[r][c] + bias[j];
            H32[(size_t)b * H_ + j] = v;
            H16[(size_t)b * H_ + j] = (_Float16)v;
        }
}

// ---------------- persistent GRU: all 128 steps in one kernel ----------------
// 512 blocks x 256 thr (4 waves), 2 blocks/CU. Block = (row-group
// m = (bid&7)|((bid>>5)&8) -> 32 rows, jt = (bid>>3)&31 -> 16 cols).
// Co-resident blocks (bid, bid+256) differ in bit8 -> DIFFERENT barrier
// groups -> one group's sync latency hides under the other's compute.
// Each 256-block half-grid (bit8) is a fully independent sub-problem ->
// deadlock-free even at 1 block/CU.
// CORRECTNESS (R10 lesson): nontemporal is only a cache HINT, not a
// coherence bypass -> cross-XCD exchange uses relaxed AGENT-scope atomics
// (global_load/store sc0 sc1: bypass L1/L2, served at L3, the shared
// coherence point). No fences, no invalidates, placement-independent.
__global__ __launch_bounds__(256, 2)
void gru_persist(const _Float16* __restrict__ Wpkh,
                 const float* __restrict__ bp,
                 const _Float16* __restrict__ h16A, _Float16* __restrict__ h16B,
                 const float* __restrict__ h0f32,
                 float* __restrict__ out,
                 unsigned int* __restrict__ flags) {
    int bid  = blockIdx.x;
    int m    = (bid & 7) | ((bid >> 5) & 8);   // row group (16 groups x 32 rows)
    int jt   = (bid >> 3) & 31;                // 0..31
    int m0   = m * 32;
    int tid  = threadIdx.x;
    int w    = tid >> 6;           // wave 0..3
    int lane = tid & 63;

    unsigned int* gflags = flags + m * 128;   // 32 flags in one 128B line

    __shared__ float red[2][2][6][64][4];     // 48 KB

    // ---- prologue: persistent W fragments (4 kt x 6 gates, fp16) ----
    half8 Wf[4][6];
#pragma unroll
    for (int kk = 0; kk < 4; ++kk) {
        int kt = 4 * w + kk;
        const _Float16* wb = &Wpkh[((size_t)(jt * 16 + kt) * 6) * 512 + lane * 8];
#pragma unroll
        for (int g = 0; g < 6; ++g)
            Wf[kk][g] = *(const half8*)&wb[(size_t)g * 512];
    }

    // ---- epilogue mapping: thread owns 2 outputs (same row, adjacent cols) --
    int o0   = tid * 2;
    int erow = o0 >> 4;            // 0..31 block-local row
    int ecol = o0 & 15;            // even col
    int gr   = m0 + erow;          // global row
    int gc0  = jt * 16 + ecol, gc1 = gc0 + 1;
    float eb0[6], eb1[6];
#pragma unroll
    for (int g = 0; g < 6; ++g) { eb0[g] = bp[g * H_ + gc0]; eb1[g] = bp[g * H_ + gc1]; }
    int emf   = erow >> 4;
    int elane = ((erow & 15) >> 2) << 4;
    int ev    = erow & 3;

    size_t i0 = (size_t)gr * H_ + gc0;     // even -> one packed u32 store
    float hp0 = h0f32[i0];
    float hp1 = h0f32[i0 + 1];

    const _Float16* cur = h16A;
    _Float16*       nxt = h16B;

    int arow  = m0 + (lane & 15);
    int akoff = (lane >> 4) * 8;

    for (int t = 0; t < TS_; ++t) {
        // ---- hoisted A-loads: agent-scope (sc0 sc1) u64 pairs, L3-coherent --
        half8 a[4][2];
#pragma unroll
        for (int kk = 0; kk < 4; ++kk) {
            int kbase = (4 * w + kk) * 32 + akoff;
#pragma unroll
            for (int mf = 0; mf < 2; ++mf) {
                const unsigned long long* p = (const unsigned long long*)
                    (cur + (size_t)(arow + 16 * mf) * H_ + kbase);
                u64x2 v;
                v[0] = __hip_atomic_load(p,     __ATOMIC_RELAXED, __HIP_MEMORY_SCOPE_AGENT);
                v[1] = __hip_atomic_load(p + 1, __ATOMIC_RELAXED, __HIP_MEMORY_SCOPE_AGENT);
                a[kk][mf] = __builtin_bit_cast(half8, v);
            }
        }

        f32x4 acc[2][6] = {};
#pragma unroll
        for (int kk = 0; kk < 4; ++kk) {
#pragma unroll
            for (int mf = 0; mf < 2; ++mf) {
                if (t > 0) {
#pragma unroll
                    for (int g = 0; g < 3; ++g)
                        acc[mf][g] = __builtin_amdgcn_mfma_f32_16x16x32_f16(a[kk][mf], Wf[kk][g], acc[mf][g], 0, 0, 0);
                }
#pragma unroll
                for (int g = 3; g < 6; ++g)
                    acc[mf][g] = __builtin_amdgcn_mfma_f32_16x16x32_f16(a[kk][mf], Wf[kk][g], acc[mf][g], 0, 0, 0);
            }
        }

        // ---- split-K reduction: 4 waves -> 2 rounds ----
        if (w >= 2) {
#pragma unroll
            for (int mf = 0; mf < 2; ++mf)
#pragma unroll
                for (int g = 0; g < 6; ++g)
                    *(f32x4*)&red[w - 2][mf][g][lane][0] = acc[mf][g];
        }
        __syncthreads();
        if (w < 2) {
#pragma unroll
            for (int mf = 0; mf < 2; ++mf)
#pragma unroll
                for (int g = 0; g < 6; ++g)
                    acc[mf][g] += *(const f32x4*)&red[w][mf][g][lane][0];
        }
        __syncthreads();
        if (w == 1) {
#pragma unroll
            for (int mf = 0; mf < 2; ++mf)
#pragma unroll
                for (int g = 0; g < 6; ++g)
                    *(f32x4*)&red[0][mf][g][lane][0] = acc[mf][g];
        }
        __syncthreads();
        if (w == 0) {
#pragma unroll
            for (int mf = 0; mf < 2; ++mf)
#pragma unroll
                for (int g = 0; g < 6; ++g) {
                    acc[mf][g] += *(const f32x4*)&red[0][mf][g][lane][0];
                    *(f32x4*)&red[1][mf][g][lane][0] = acc[mf][g];
                }
        }
        __syncthreads();

        // ---- epilogue: gate math, 2 outputs/thread, hp carried in registers --
        {
            float v0[6], v1[6];
#pragma unroll
            for (int g = 0; g < 6; ++g) {
                v0[g] = red[1][emf][g][elane + ecol][ev];
                v1[g] = red[1][emf][g][elane + ecol + 1][ev];
            }
            float rg0 = 1.f / (1.f + expf(-((v0[0] + eb0[0]) + (v0[3] + eb0[3]))));
            float zg0 = 1.f / (1.f + expf(-((v0[1] + eb0[1]) + (v0[4] + eb0[4]))));
            float ng0 = tanhf((v0[2] + eb0[2]) + rg0 * (v0[5] + eb0[5]));
            float hn0 = (1.f - zg0) * ng0 + zg0 * hp0;

            float rg1 = 1.f / (1.f + expf(-((v1[0] + eb1[0]) + (v1[3] + eb1[3]))));
            float zg1 = 1.f / (1.f + expf(-((v1[1] + eb1[1]) + (v1[4] + eb1[4]))));
            float ng1 = tanhf((v1[2] + eb1[2]) + rg1 * (v1[5] + eb1[5]));
            float hn1 = (1.f - zg1) * ng1 + zg1 * hp1;

            // packed agent-scope store of both adjacent fp16 h values
            unsigned short s0 = __builtin_bit_cast(unsigned short, (_Float16)hn0);
            unsigned short s1 = __builtin_bit_cast(unsigned short, (_Float16)hn1);
            unsigned pk = (unsigned)s0 | ((unsigned)s1 << 16);
            __hip_atomic_store((unsigned*)(nxt + i0), pk,
                               __ATOMIC_RELAXED, __HIP_MEMORY_SCOPE_AGENT);
            size_t oo = (size_t)gr * (TS_ * H_) + (size_t)t * H_;
            __builtin_nontemporal_store(hn0, &out[oo + gc0]);
            __builtin_nontemporal_store(hn1, &out[oo + gc1]);
            hp0 = hn0; hp1 = hn1;
        }

        if (t < TS_ - 1) {
            asm volatile("s_waitcnt vmcnt(0)" ::: "memory");   // h stores acked at L3
            __syncthreads();                                   // also guards red[] reuse
            if (tid == 0)
                __hip_atomic_store(&gflags[jt], (unsigned)(t + 1),
                                   __ATOMIC_RELAXED, __HIP_MEMORY_SCOPE_AGENT);
            if (w == 0 && lane < 32) {
                unsigned target = (unsigned)(t + 1);
                while (__hip_atomic_load(&gflags[lane], __ATOMIC_RELAXED,
                                         __HIP_MEMORY_SCOPE_AGENT) < target)
                    __builtin_amdgcn_s_sleep(1);
            }
            __syncthreads();
            const _Float16* tc = cur;
            cur = nxt; nxt = (_Float16*)tc;
        }
    }
}

extern "C" void kernel_launch(void* const* d_in, const int* in_sizes, int n_in,
                              void* d_out, int out_size, void* d_ws, size_t ws_size,
                              hipStream_t stream) {
    const float* x     = (const float*)d_in[0];
    const float* W_lin = (const float*)d_in[1];
    const float* b_lin = (const float*)d_in[2];
    const float* W_ih  = (const float*)d_in[3];
    const float* W_hh  = (const float*)d_in[4];
    const float* b_ih  = (const float*)d_in[5];
    const float* b_hh  = (const float*)d_in[6];
    float* out = (float*)d_out;

    char* wsb = (char*)d_ws;
    _Float16* Wpkh  = (_Float16*)(wsb);              // 3145728 B
    float*    WlinT = (float*)(wsb + 3145728);       // 2097152 B
    float*    bp    = (float*)(wsb + 5242880);       // 12288 B
    _Float16* h16A  = (_Float16*)(wsb + 5255168);    // 524288 B
    _Float16* h16B  = (_Float16*)(wsb + 5779456);    // 524288 B
    float*    h0f32 = (float*)(wsb + 6303744);       // 1048576 B
    unsigned int* flags = (unsigned int*)(wsb + 7352320);  // 16 x 128 uints

    hipMemcpyAsync(bp,        b_ih, 1536 * sizeof(float), hipMemcpyDeviceToDevice, stream);
    hipMemcpyAsync(bp + 1536, b_hh, 1536 * sizeof(float), hipMemcpyDeviceToDevice, stream);
    hipMemsetAsync(flags, 0, 16 * 128 * sizeof(unsigned int), stream);

    pack_weights <<<dim3(32, 16), 384, 0, stream>>>(W_ih, W_hh, Wpkh);
    transpose_lin<<<dim3(16, 32), dim3(32, 8), 0, stream>>>(W_lin, WlinT);

    gemm_h0<<<dim3(16, 16), 256, 0, stream>>>(x, WlinT, b_lin, h16A, h0f32);

    gru_persist<<<512, 256, 0, stream>>>(Wpkh, bp, h16A, h16B, h0f32, out, flags);
}